// Round 10
// baseline (168.790 us; speedup 1.0000x reference)
//
#include <hip/hip_runtime.h>
#include <math.h>

typedef __attribute__((ext_vector_type(8))) short short8;
typedef __attribute__((ext_vector_type(4))) float f32x4;
typedef __attribute__((ext_vector_type(16))) float f32x16;

#define NTAP 125
#define DCH 32

static __device__ __forceinline__ unsigned short f2bf(float f) {
    union { float f; unsigned u; } v; v.f = f;
    unsigned u = v.u;
    return (unsigned short)((u + 0x7FFFu + ((u >> 16) & 1u)) >> 16);
}

static __device__ __forceinline__ void gld_lds16(const void* g, void* l) {
    __builtin_amdgcn_global_load_lds(
        (const __attribute__((address_space(1))) unsigned int*)g,
        (__attribute__((address_space(3))) unsigned int*)l, 16, 0, 0);
}

// ---------------------------------------------------------------------------
// Kernel 1 (fused build+pack): build conv weights for tap t in LDS, then
// pack to bf16 B-fragments kwb[tap][kh][lane][8] for mfma_f32_32x32x16_bf16.
// Skip connection folded into center tap 62. (math verified R0-R9)
// ---------------------------------------------------------------------------
__global__ __launch_bounds__(128) void build_pack(
    const float* __restrict__ weight,
    const float* __restrict__ w_sc0,
    const float* __restrict__ w_sc1,
    unsigned short* __restrict__ kwb)
{
    const int t = blockIdx.x;
    const int dx = t / 25, dy = (t / 5) % 5, dz = t % 5;
    const float px = dx - 2.0f, py = dy - 2.0f, pz = dz - 2.0f;
    const float d = sqrtf(px * px + py * py + pz * pz);

    const float stepv = 2.5f / 6.0f;
    const float embc = 1.14136f * expf(2.0f);
    float emb[5];
#pragma unroll
    for (int n = 0; n < 5; ++n) {
        float diff = (d - stepv * (float)(n + 1)) / stepv;
        float a = diff + 1.0f, bb = 1.0f - diff;
        float v = 0.0f;
        if (a > 0.0f && bb > 0.0f)
            v = embc * expf(-1.0f / a) * expf(-1.0f / bb);
        emb[n] = v;
    }

    const float inv_d = (d > 0.0f) ? 1.0f / d : 0.0f;
    const float ux = px * inv_d, uy = py * inv_d, uz = pz * inv_d;
    const float s3 = 1.73205081f, s5 = 2.23606798f, s15 = 3.87298335f;
    float sh[9];
    sh[0] = 1.0f;
    sh[1] = s3 * ux; sh[2] = s3 * uy; sh[3] = s3 * uz;
    sh[4] = s15 * ux * uz;
    sh[5] = s15 * ux * uy;
    sh[6] = s5 * (uy * uy - 0.5f * (ux * ux + uz * uz));
    sh[7] = s15 * uy * uz;
    sh[8] = 0.5f * s15 * (uz * uz - ux * ux);

    const float i_s2 = 0.70710678f, i_s6 = 0.40824829f, i_s5 = 0.44721360f;
    float T[3][3];
    T[0][0] = i_s5 * (-sh[6] * i_s6 - sh[8] * i_s2);
    T[0][1] = i_s5 * (sh[5] * i_s2);
    T[0][2] = i_s5 * (sh[4] * i_s2);
    T[1][0] = T[0][1];
    T[1][1] = i_s5 * (2.0f * sh[6] * i_s6);
    T[1][2] = i_s5 * (sh[7] * i_s2);
    T[2][0] = T[0][2];
    T[2][1] = T[1][2];
    T[2][2] = i_s5 * (-sh[6] * i_s6 + sh[8] * i_s2);

    __shared__ float Wt[320];
    __shared__ float kws[1024];              // [ci=32][co=32] for this tap
    for (int col = threadIdx.x; col < 320; col += 128) {
        float a = 0.0f;
#pragma unroll
        for (int n = 0; n < 5; ++n) a += emb[n] * weight[n * 320 + col];
        Wt[col] = a * (1.0f / 125.0f);
    }
    __syncthreads();

    const float pw0 = 0.25f;
    const float pw1 = 0.35355339f;
    const float inv_s3 = 0.57735027f;
    const float inv_s8 = 0.35355339f;

    for (int idx = threadIdx.x; idx < 1024; idx += 128) {
        const int o = idx >> 5, i = idx & 31;
        float val;
        if (o < 8) {
            if (i < 8) {
                val = pw0 * Wt[i * 8 + o];
            } else {
                const int u = (i - 8) / 3, m = (i - 8) % 3;
                val = pw0 * inv_s3 * Wt[192 + u * 8 + o] * sh[1 + m];
            }
        } else {
            const int v = (o - 8) / 3, k = (o - 8) % 3;
            if (i < 8) {
                val = pw1 * inv_s3 * Wt[64 + i * 8 + v] * sh[1 + k];
            } else {
                const int u = (i - 8) / 3, m = (i - 8) % 3;
                float tv = Wt[256 + u * 8 + v] * T[m][k];
                if (m == k) tv += inv_s3 * Wt[128 + u * 8 + v];
                val = pw1 * tv;
            }
        }
        if (t == 62) {
            if (o < 8 && i < 8) {
                val += inv_s8 * w_sc0[i * 8 + o];
            } else if (o >= 8 && i >= 8) {
                const int u = (i - 8) / 3, m = (i - 8) % 3;
                const int v = (o - 8) / 3, k = (o - 8) % 3;
                if (m == k) val += inv_s8 * w_sc1[u * 8 + v];
            }
        }
        kws[i * 32 + o] = val;
    }
    __syncthreads();

    // pack: kwb[tap][kh][lane][8], ci = kh*16 + (l>>5)*8 + j, co = l&31
    const int tid = threadIdx.x;
    const int kh = tid >> 6, l = tid & 63;
    const int co = l & 31;
    const int cib = kh * 16 + (l >> 5) * 8;
    unsigned short v[8];
#pragma unroll
    for (int j = 0; j < 8; ++j)
        v[j] = f2bf(kws[(cib + j) * 32 + co]);
    uint4 o;
    o.x = (unsigned)v[0] | ((unsigned)v[1] << 16);
    o.y = (unsigned)v[2] | ((unsigned)v[3] << 16);
    o.z = (unsigned)v[4] | ((unsigned)v[5] << 16);
    o.w = (unsigned)v[6] | ((unsigned)v[7] << 16);
    *reinterpret_cast<uint4*>(kwb + ((size_t)(t * 2 + kh) * 64 + l) * 8) = o;
}

// ---------------------------------------------------------------------------
// Kernel 2: transpose x fp32 [b][ci][X][Y][Z] -> bf16 xt[b][64][64][68][32]
// with z-halo of 2 each side (z_idx = z + 2), halo zero-filled here.
// (verified R5: passed with absmax 0.03125)
// ---------------------------------------------------------------------------
__global__ __launch_bounds__(256) void xpose(
    const float* __restrict__ x, unsigned short* __restrict__ xt)
{
    const int xx = blockIdx.x, yy = blockIdx.y, b = blockIdx.z;
    const int t = threadIdx.x;
    const int z = t & 63, part = t >> 6;
    const float* src = x + ((((size_t)b * 32) * 64 + xx) * 64 + yy) * 64 + z;
    unsigned short v[8];
#pragma unroll
    for (int j = 0; j < 8; ++j)
        v[j] = f2bf(src[(size_t)(part * 8 + j) * 262144]);
    uint4 o;
    o.x = (unsigned)v[0] | ((unsigned)v[1] << 16);
    o.y = (unsigned)v[2] | ((unsigned)v[3] << 16);
    o.z = (unsigned)v[4] | ((unsigned)v[5] << 16);
    o.w = (unsigned)v[6] | ((unsigned)v[7] << 16);
    unsigned short* row =
        xt + (((size_t)b * 64 + xx) * 64 + yy) * 2176;   // 68*32 shorts/row
    *reinterpret_cast<uint4*>(row + (size_t)(z + 2) * 32 + part * 8) = o;
    if (t < 16) {
        const int zi = t >> 2;                     // 0..3
        const int z_idx = (zi < 2) ? zi : 64 + zi; // 0,1,66,67
        uint4 zz; zz.x = zz.y = zz.z = zz.w = 0u;
        *reinterpret_cast<uint4*>(row + (size_t)z_idx * 32 + (t & 3) * 8) = zz;
    }
}

__global__ void zero_fill(float4* p) {
    float4 z = make_float4(0.f, 0.f, 0.f, 0.f);
#pragma unroll
    for (int i = 0; i < 4; ++i) p[threadIdx.x + 256 * i] = z;
}

// ---------------------------------------------------------------------------
// Kernel 3: implicit-GEMM conv via mfma_f32_32x32x16_bf16.
// R10: A never touches LDS. R0-R9 established the plateau (~7600 cyc/step,
// 44-46% MfmaUtil) is the per-wave serial chain of LDS A-read round-trips;
// waves on a SIMD sum their serial times under every schedule tried.
// Fix: A-fragments loaded direct from z-halo-padded xt (R5-verified
// addressing) into REGISTERS, prefetched one HALF-STEP ahead (issue half
// H+1's 10 frags before computing half H from the other reg buffer) —
// ~2000-cyc distance hides L1/L2 latency (R5 failed only because it had
// no prefetch distance). LDS holds only Bs (51200 B static, restaged per
// dy between two __syncthreads). NO barriers inside a dy -> waves
// free-run and desync naturally; setprio(1) around MFMA clusters (T5's
// correct regime). Per-CU LDS traffic/step: 360 -> 200 reads; A 2-way
// bank conflicts gone; per-wave critical path has zero LDS-A latency.
// Block 512 thr (8 waves), tile 4x*8y*64z, grid 16*8*2 = 256 = 1/CU.
// Regs: acc 128 + A dbuf 2x2x5 x 4 = 80 -> ~230, fits 2 waves/SIMD.
// ---------------------------------------------------------------------------
__global__ __launch_bounds__(512, 2) void conv_mfma(
    const unsigned short* __restrict__ xt,   // [b][64][64][68][32] bf16 halo
    const unsigned short* __restrict__ kwb,  // [125][2][64][8]
    const unsigned short* __restrict__ zpg,  // 16 KB zeros
    float* __restrict__ out)                 // [b][32][64][64][64]
{
    __shared__ unsigned short Bs[25600];     // 51200 B: [25 tap][2 kh][64][16B]

    const int tid = threadIdx.x;
    const int lane = tid & 63;
    const int wv = tid >> 6;                 // 0..7
    const int oyp = wv >> 1, zh = wv & 1;    // oy pair 0..3, z half
    const int x0 = blockIdx.x * 4, y0 = blockIdx.y * 8;
    const int b = blockIdx.z;
    const int l31 = lane & 31, hi = lane >> 5;

    // per-lane base within an (xx,yy) row: z_idx*32 + hi*8 shorts.
    // A frag for (dz,kh) at row base + dz*64 + kh*32 bytes (R5-verified).
    const int lanebase = (zh * 32 + l31) * 32 + hi * 8;
    const char* bsp = (const char*)Bs;
    const int bbase = lane * 16;

    // Bs staging precompute: 3200 chunks, c = tid + k*512
    int bsrc[7];
#pragma unroll
    for (int k = 0; k < 7; ++k) {
        const int c = tid + k * 512;
        const int tp = c >> 7, rem = c & 127;
        const int dxx = tp / 5, dzz = tp - dxx * 5;
        bsrc[k] = (dxx * 25 + dzz) * 128 + rem;
    }

    auto issue_bs = [&](int dy) {
#pragma unroll
        for (int k = 0; k < 7; ++k) {
            const int c0 = wv * 64 + k * 512;   // wave-uniform dest base
            if (c0 < 3200) {
                gld_lds16(kwb + ((size_t)(bsrc[k] + dy * 640)) * 8,
                          (char*)Bs + c0 * 16);
            }
        }
    };

    // A prefetch double buffer: [kh][oy][dz], all statically indexed.
    short8 Ab[2][2][5];

    f32x16 acc[2][4];
#pragma unroll
    for (int oyi = 0; oyi < 2; ++oyi)
#pragma unroll
        for (int ox = 0; ox < 4; ++ox)
#pragma unroll
            for (int e = 0; e < 16; ++e) acc[oyi][ox][e] = 0.0f;

// Issue the 10 A-fragment loads for half (DYN, XLN, KH) into Ab[KH].
#define ISSUE_A(DYN, XLN, KH)                                                \
    {                                                                        \
        const int xx_ = x0 + (XLN) - 2;                                      \
        const int yy0_ = y0 + oyp * 2 + (DYN) - 2;                           \
        const bool xok_ = ((unsigned)xx_ < 64u);                             \
        const long long sb_ =                                                \
            ((long long)(b * 64 + xx_) * 64) * 2176 + lanebase;              \
        const unsigned short* p0_ = (xok_ && (unsigned)yy0_ < 64u)           \
            ? xt + sb_ + (long long)yy0_ * 2176 : zpg + lanebase;            \
        const unsigned short* p1_ = (xok_ && (unsigned)(yy0_ + 1) < 64u)     \
            ? xt + sb_ + (long long)(yy0_ + 1) * 2176 : zpg + lanebase;      \
        _Pragma("unroll")                                                    \
        for (int dz_ = 0; dz_ < 5; ++dz_) {                                  \
            Ab[KH][0][dz_] = *reinterpret_cast<const short8*>(               \
                reinterpret_cast<const char*>(p0_) + dz_ * 64 + (KH) * 32);  \
            Ab[KH][1][dz_] = *reinterpret_cast<const short8*>(               \
                reinterpret_cast<const char*>(p1_) + dz_ * 64 + (KH) * 32);  \
        }                                                                    \
    }

// Compute half (xl=XL, kh=KH) from Ab[KH]; B shared across the oy pair.
#define COMPUTE_HALF(XL, KH)                                                 \
    {                                                                        \
        _Pragma("unroll")                                                    \
        for (int dz_ = 0; dz_ < 5; ++dz_) {                                  \
            const short8 a0_ = Ab[KH][0][dz_];                               \
            const short8 a1_ = Ab[KH][1][dz_];                               \
            __builtin_amdgcn_s_setprio(1);                                   \
            _Pragma("unroll")                                                \
            for (int ox_ = 0; ox_ < 4; ++ox_) {                              \
                const int dxv_ = (XL) - ox_;                                 \
                if (dxv_ < 0 || dxv_ > 4) continue;                          \
                const short8 bf_ = *reinterpret_cast<const short8*>(         \
                    bsp + bbase + (((dxv_ * 5 + dz_) * 2 + (KH)) << 10));    \
                acc[0][ox_] = __builtin_amdgcn_mfma_f32_32x32x16_bf16(       \
                    a0_, bf_, acc[0][ox_], 0, 0, 0);                         \
                acc[1][ox_] = __builtin_amdgcn_mfma_f32_32x32x16_bf16(       \
                    a1_, bf_, acc[1][ox_], 0, 0, 0);                         \
            }                                                                \
            __builtin_amdgcn_s_setprio(0);                                   \
        }                                                                    \
    }

    // prologue: Bs(0) staged; first half's A issued; one full drain.
    issue_bs(0);
    ISSUE_A(0, 0, 0);
    __syncthreads();

    for (int dy = 0; dy < 5; ++dy) {
        if (dy > 0) {
            // Bs(dy) restage between barriers (readers of Bs(dy-1) done;
            // staged data visible after 2nd). The in-flight A prefetch is
            // drained here too (issued a half earlier -> already landed).
            __syncthreads();
            issue_bs(dy);
            __syncthreads();
        }
#pragma unroll
        for (int xl = 0; xl < 8; ++xl) {
            // issue A for (dy, xl, kh=1); compute (dy, xl, kh=0)
            ISSUE_A(dy, xl, 1);
            COMPUTE_HALF(xl, 0);
            // issue A for next half-step pair's kh=0; compute kh=1
            if (xl < 7) {
                ISSUE_A(dy, xl + 1, 0);
            } else if (dy < 4) {
                ISSUE_A(dy + 1, 0, 0);
            }
            COMPUTE_HALF(xl, 1);
        }
    }
#undef ISSUE_A
#undef COMPUTE_HALF

    // epilogue: D lane l: co = l&31, z = zh*32 + rq*8 + (l>>5)*4 + (r&3)
#pragma unroll
    for (int oyi = 0; oyi < 2; ++oyi) {
        const int yy = y0 + oyp * 2 + oyi;
#pragma unroll
        for (int ox = 0; ox < 4; ++ox) {
            float* base = out +
                ((((size_t)b * 32 + l31) * 64 + (x0 + ox)) * 64 + yy) * 64 +
                zh * 32 + hi * 4;
#pragma unroll
            for (int rq = 0; rq < 4; ++rq) {
                f32x4 v = { acc[oyi][ox][rq * 4 + 0], acc[oyi][ox][rq * 4 + 1],
                            acc[oyi][ox][rq * 4 + 2], acc[oyi][ox][rq * 4 + 3] };
                *reinterpret_cast<f32x4*>(base + rq * 8) = v;
            }
        }
    }
}

// ---------------------------------------------------------------------------
extern "C" void kernel_launch(void* const* d_in, const int* in_sizes, int n_in,
                              void* d_out, int out_size, void* d_ws, size_t ws_size,
                              hipStream_t stream) {
    const float* x      = (const float*)d_in[0];
    const float* weight = (const float*)d_in[1];
    const float* w_sc0  = (const float*)d_in[2];
    const float* w_sc1  = (const float*)d_in[3];
    float* out = (float*)d_out;

    char* ws = (char*)d_ws;
    unsigned short* xt  = (unsigned short*)ws;                 // 35,651,584 B
    unsigned short* kwb = (unsigned short*)(ws + 35651584);    //    256,000 B
    unsigned short* zpg = (unsigned short*)(ws + 35907584);    //     16,384 B

    hipLaunchKernelGGL(build_pack, dim3(NTAP), dim3(128), 0, stream,
                       weight, w_sc0, w_sc1, kwb);
    hipLaunchKernelGGL(xpose, dim3(64, 64, 2), dim3(256), 0, stream, x, xt);
    hipLaunchKernelGGL(zero_fill, dim3(1), dim3(256), 0, stream, (float4*)zpg);
    hipLaunchKernelGGL(conv_mfma, dim3(16, 8, 2), dim3(512), 0, stream,
                       xt, kwb, zpg, out);
}

// Round 11
// 144.074 us; speedup vs baseline: 1.1715x; 1.1715x over previous
//
#include <hip/hip_runtime.h>
#include <math.h>

typedef __attribute__((ext_vector_type(8))) short short8;
typedef __attribute__((ext_vector_type(4))) float f32x4;
typedef __attribute__((ext_vector_type(16))) float f32x16;

#define NTAP 125
#define DCH 32

static __device__ __forceinline__ unsigned short f2bf(float f) {
    union { float f; unsigned u; } v; v.f = f;
    unsigned u = v.u;
    return (unsigned short)((u + 0x7FFFu + ((u >> 16) & 1u)) >> 16);
}

static __device__ __forceinline__ void gld_lds16(const void* g, void* l) {
    __builtin_amdgcn_global_load_lds(
        (const __attribute__((address_space(1))) unsigned int*)g,
        (__attribute__((address_space(3))) unsigned int*)l, 16, 0, 0);
}

// ---------------------------------------------------------------------------
// Kernel 1 (fused build+pack): build conv weights for tap t in LDS, then
// pack to bf16 B-fragments kwb[tap][kh][lane][8] for mfma_f32_32x32x16_bf16.
// Skip connection folded into center tap 62. (math verified R0-R10)
// Block 0 additionally zero-fills the 4 KB zero-page (folds the old
// zero_fill launch; stream-ordered before conv).
// ---------------------------------------------------------------------------
__global__ __launch_bounds__(128) void build_pack(
    const float* __restrict__ weight,
    const float* __restrict__ w_sc0,
    const float* __restrict__ w_sc1,
    unsigned short* __restrict__ kwb,
    float4* __restrict__ zpg)
{
    const int t = blockIdx.x;
    if (t == 0) {
        float4 z4 = make_float4(0.f, 0.f, 0.f, 0.f);
        zpg[threadIdx.x * 2] = z4;
        zpg[threadIdx.x * 2 + 1] = z4;
    }
    const int dx = t / 25, dy = (t / 5) % 5, dz = t % 5;
    const float px = dx - 2.0f, py = dy - 2.0f, pz = dz - 2.0f;
    const float d = sqrtf(px * px + py * py + pz * pz);

    const float stepv = 2.5f / 6.0f;
    const float embc = 1.14136f * expf(2.0f);
    float emb[5];
#pragma unroll
    for (int n = 0; n < 5; ++n) {
        float diff = (d - stepv * (float)(n + 1)) / stepv;
        float a = diff + 1.0f, bb = 1.0f - diff;
        float v = 0.0f;
        if (a > 0.0f && bb > 0.0f)
            v = embc * expf(-1.0f / a) * expf(-1.0f / bb);
        emb[n] = v;
    }

    const float inv_d = (d > 0.0f) ? 1.0f / d : 0.0f;
    const float ux = px * inv_d, uy = py * inv_d, uz = pz * inv_d;
    const float s3 = 1.73205081f, s5 = 2.23606798f, s15 = 3.87298335f;
    float sh[9];
    sh[0] = 1.0f;
    sh[1] = s3 * ux; sh[2] = s3 * uy; sh[3] = s3 * uz;
    sh[4] = s15 * ux * uz;
    sh[5] = s15 * ux * uy;
    sh[6] = s5 * (uy * uy - 0.5f * (ux * ux + uz * uz));
    sh[7] = s15 * uy * uz;
    sh[8] = 0.5f * s15 * (uz * uz - ux * ux);

    const float i_s2 = 0.70710678f, i_s6 = 0.40824829f, i_s5 = 0.44721360f;
    float T[3][3];
    T[0][0] = i_s5 * (-sh[6] * i_s6 - sh[8] * i_s2);
    T[0][1] = i_s5 * (sh[5] * i_s2);
    T[0][2] = i_s5 * (sh[4] * i_s2);
    T[1][0] = T[0][1];
    T[1][1] = i_s5 * (2.0f * sh[6] * i_s6);
    T[1][2] = i_s5 * (sh[7] * i_s2);
    T[2][0] = T[0][2];
    T[2][1] = T[1][2];
    T[2][2] = i_s5 * (-sh[6] * i_s6 + sh[8] * i_s2);

    __shared__ float Wt[320];
    __shared__ float kws[1024];              // [ci=32][co=32] for this tap
    for (int col = threadIdx.x; col < 320; col += 128) {
        float a = 0.0f;
#pragma unroll
        for (int n = 0; n < 5; ++n) a += emb[n] * weight[n * 320 + col];
        Wt[col] = a * (1.0f / 125.0f);
    }
    __syncthreads();

    const float pw0 = 0.25f;
    const float pw1 = 0.35355339f;
    const float inv_s3 = 0.57735027f;
    const float inv_s8 = 0.35355339f;

    for (int idx = threadIdx.x; idx < 1024; idx += 128) {
        const int o = idx >> 5, i = idx & 31;
        float val;
        if (o < 8) {
            if (i < 8) {
                val = pw0 * Wt[i * 8 + o];
            } else {
                const int u = (i - 8) / 3, m = (i - 8) % 3;
                val = pw0 * inv_s3 * Wt[192 + u * 8 + o] * sh[1 + m];
            }
        } else {
            const int v = (o - 8) / 3, k = (o - 8) % 3;
            if (i < 8) {
                val = pw1 * inv_s3 * Wt[64 + i * 8 + v] * sh[1 + k];
            } else {
                const int u = (i - 8) / 3, m = (i - 8) % 3;
                float tv = Wt[256 + u * 8 + v] * T[m][k];
                if (m == k) tv += inv_s3 * Wt[128 + u * 8 + v];
                val = pw1 * tv;
            }
        }
        if (t == 62) {
            if (o < 8 && i < 8) {
                val += inv_s8 * w_sc0[i * 8 + o];
            } else if (o >= 8 && i >= 8) {
                const int u = (i - 8) / 3, m = (i - 8) % 3;
                const int v = (o - 8) / 3, k = (o - 8) % 3;
                if (m == k) val += inv_s8 * w_sc1[u * 8 + v];
            }
        }
        kws[i * 32 + o] = val;
    }
    __syncthreads();

    // pack: kwb[tap][kh][lane][8], ci = kh*16 + (l>>5)*8 + j, co = l&31
    const int tid = threadIdx.x;
    const int kh = tid >> 6, l = tid & 63;
    const int co = l & 31;
    const int cib = kh * 16 + (l >> 5) * 8;
    unsigned short v[8];
#pragma unroll
    for (int j = 0; j < 8; ++j)
        v[j] = f2bf(kws[(cib + j) * 32 + co]);
    uint4 o;
    o.x = (unsigned)v[0] | ((unsigned)v[1] << 16);
    o.y = (unsigned)v[2] | ((unsigned)v[3] << 16);
    o.z = (unsigned)v[4] | ((unsigned)v[5] << 16);
    o.w = (unsigned)v[6] | ((unsigned)v[7] << 16);
    *reinterpret_cast<uint4*>(kwb + ((size_t)(t * 2 + kh) * 64 + l) * 8) = o;
}

// ---------------------------------------------------------------------------
// Kernel 2: transpose x fp32 [b][ci][X][Y][Z] -> bf16 x_t[b][X][Y][Z][ci=32]
// ---------------------------------------------------------------------------
__global__ __launch_bounds__(256) void xpose(
    const float* __restrict__ x, unsigned short* __restrict__ xt)
{
    const int xx = blockIdx.x, yy = blockIdx.y, b = blockIdx.z;
    const int t = threadIdx.x;
    const int z = t & 63, part = t >> 6;
    const float* src = x + ((((size_t)b * 32) * 64 + xx) * 64 + yy) * 64 + z;
    unsigned short v[8];
#pragma unroll
    for (int j = 0; j < 8; ++j)
        v[j] = f2bf(src[(size_t)(part * 8 + j) * 262144]);
    uint4 o;
    o.x = (unsigned)v[0] | ((unsigned)v[1] << 16);
    o.y = (unsigned)v[2] | ((unsigned)v[3] << 16);
    o.z = (unsigned)v[4] | ((unsigned)v[5] << 16);
    o.w = (unsigned)v[6] | ((unsigned)v[7] << 16);
    *reinterpret_cast<uint4*>(
        xt + ((((size_t)b * 64 + xx) * 64 + yy) * 64 + z) * 32 + part * 8) = o;
}

// ---------------------------------------------------------------------------
// Kernel 3: implicit-GEMM conv via mfma_f32_32x32x16_bf16.
// R11 = exact R3 conv structure (best measured: 126.0 us, MfmaUtil ~46%).
// 2-phase double-buffered slab on global_load_lds; prefetch of step t+1
// issued at the TOP of step t into buf[(xl&1)^1]; single __syncthreads at
// END of step; Bs restaged per dy behind a counted vmcnt mid-barrier.
// R9's stagger+setprio removed (A/B: they cost ~3 us on conv).
// Structural note (R0-R10): conv is pinned at ~7600 cyc/step because each
// wave's serial chain (ds_read issue -> lgkm wait -> MFMA wave-block, x10
// groups) makes the CU's LDS pipe (~4900 cyc/step) and the SIMD matrix
// pipes (3228 cyc/step) largely serialize; schedule variants (sync
// flavor, counted waits, asm reads, phase stagger, occupancy, read count,
// direct-global A) all land 126-150 us. This is the best-known point.
// Block 512 thr (8 waves), tile 4x*8y*64z, grid 16*8*2 = 256 = 1 block/CU.
// LDS 120832 B: Bs[25][2][64][16B] (51200) + slab dbuf 2 x 34816.
// ---------------------------------------------------------------------------
__global__ __launch_bounds__(512, 2) void conv_mfma(
    const unsigned short* __restrict__ xt,   // [b][64][64][64][32] bf16
    const unsigned short* __restrict__ kwb,  // [125][2][64][8]
    const unsigned short* __restrict__ zpage,
    float* __restrict__ out)                 // [b][32][64][64][64]
{
    extern __shared__ unsigned short smem[];
    char* lds = (char*)smem;

    const int tid = threadIdx.x;
    const int lane = tid & 63;
    const int wv = tid >> 6;                 // 0..7
    const int oyp = wv >> 1, zh = wv & 1;    // oy pair 0..3, z half
    const int x0 = blockIdx.x * 4, y0 = blockIdx.y * 8;
    const int b = blockIdx.z;
    const int l31 = lane & 31, hi = lane >> 5;

    // A-read base (slab buf0, oyi=0); oyi=1: +4352, buf1: +34816 (imm-folded)
    int abase[5][2];
#pragma unroll
    for (int dz = 0; dz < 5; ++dz) {
        const int s = zh * 32 + l31 + dz;
#pragma unroll
        for (int kh = 0; kh < 2; ++kh) {
            const int cph = (kh * 2 + hi) ^ ((s >> 1) & 3);
            abase[dz][kh] =
                51200 + ((((oyp * 2 * 68 + s) << 2) | cph) << 4);
        }
    }
    const int bbase = lane * 16;

    // slab staging precompute: 2176 chunks, c = tid + p*512
    // (p<4 all threads; p==4 only waves 0-1)
    int srow[5]; int soff[5]; bool szok[5];
#pragma unroll
    for (int p = 0; p < 5; ++p) {
        const int c = tid + p * 512;
        const int row = c / 272;
        const int rem = c - row * 272;
        const int slot = rem >> 2;
        const int clog = (rem & 3) ^ ((slot >> 1) & 3);
        const int z = slot - 2;
        srow[p] = row;
        szok[p] = ((unsigned)z < 64u);
        soff[p] = row * 2048 + z * 32 + clog * 8;
    }

    // Bs staging precompute: 3200 chunks, c = tid + k*512
    int bsrc[7];
#pragma unroll
    for (int k = 0; k < 7; ++k) {
        const int c = tid + k * 512;
        const int tp = c >> 7, rem = c & 127;
        const int dxx = tp / 5, dzz = tp - dxx * 5;
        bsrc[k] = (dxx * 25 + dzz) * 128 + rem;
    }

    auto issue_bs = [&](int dy) {
#pragma unroll
        for (int k = 0; k < 7; ++k) {
            const int c0 = wv * 64 + k * 512;   // wave-uniform dest base
            if (c0 < 3200) {
                gld_lds16(kwb + ((size_t)(bsrc[k] + dy * 640)) * 8,
                          lds + c0 * 16);
            }
        }
    };

    auto issue_slab = [&](int dyn, int xln, int bufi) {
        const int yyb = y0 + dyn - 2;
        const int xx = x0 + xln - 2;
        const bool xok = ((unsigned)xx < 64u);
        const long long xyb =
            (long long)(b * 64 + xx) * 131072 + (long long)yyb * 2048;
        char* dst = lds + 51200 + bufi * 34816;
#pragma unroll
        for (int p = 0; p < 4; ++p) {
            const int yy = yyb + srow[p];
            const bool ok = xok && ((unsigned)yy < 64u) && szok[p];
            const unsigned short* src = ok ? (xt + xyb + soff[p]) : zpage;
            gld_lds16(src, dst + (wv * 64 + p * 512) * 16);
        }
        if (wv < 2) {   // chunks 2048..2175
            const int yy = yyb + srow[4];
            const bool ok = xok && ((unsigned)yy < 64u) && szok[4];
            const unsigned short* src = ok ? (xt + xyb + soff[4]) : zpage;
            gld_lds16(src, dst + (wv * 64 + 2048) * 16);
        }
    };

    f32x16 acc[2][4];
#pragma unroll
    for (int oyi = 0; oyi < 2; ++oyi)
#pragma unroll
        for (int ox = 0; ox < 4; ++ox)
#pragma unroll
            for (int e = 0; e < 16; ++e) acc[oyi][ox][e] = 0.0f;

    // prologue: Bs(0) + slab(0,0) -> buf0, full drain
    issue_bs(0);
    issue_slab(0, 0, 0);
    __syncthreads();

    for (int dy = 0; dy < 5; ++dy) {
#pragma unroll
        for (int xl = 0; xl < 8; ++xl) {
            if (xl == 0) {
                if (dy > 0) {
                    // restage Bs(dy) (prev readers done at last syncthreads)
                    issue_bs(dy);
                    __builtin_amdgcn_sched_barrier(0);
                    // prefetch slab(dy,1) -> buf1 (stays in flight)
                    issue_slab(dy, 1, 1);
                    __builtin_amdgcn_sched_barrier(0);
                    // counted wait: retire Bs, keep slab prefetch in flight
                    if (wv < 2)
                        asm volatile("s_waitcnt vmcnt(5)" ::: "memory");
                    else
                        asm volatile("s_waitcnt vmcnt(4)" ::: "memory");
                    __builtin_amdgcn_s_barrier();
                    __builtin_amdgcn_sched_barrier(0);
                } else {
                    // dy==0: Bs(0)+slab(0,0) visible from prologue barrier
                    issue_slab(0, 1, 1);
                }
            } else if (!(dy == 4 && xl == 7)) {
                // prefetch next step's slab into the other buffer
                issue_slab(xl == 7 ? dy + 1 : dy, xl == 7 ? 0 : xl + 1,
                           (xl & 1) ^ 1);
            }

            // compute from buf[xl&1] (boff is a compile-time immediate)
            const int boff = (xl & 1) * 34816;
#pragma unroll
            for (int dz = 0; dz < 5; ++dz) {
#pragma unroll
                for (int kh = 0; kh < 2; ++kh) {
                    const short8 a0 = *reinterpret_cast<const short8*>(
                        lds + abase[dz][kh] + boff);
                    const short8 a1 = *reinterpret_cast<const short8*>(
                        lds + abase[dz][kh] + boff + 4352);
#pragma unroll
                    for (int ox = 0; ox < 4; ++ox) {
                        const int dxv = xl - ox;
                        if (dxv < 0 || dxv > 4) continue;
                        const short8 bf = *reinterpret_cast<const short8*>(
                            lds + bbase + (((dxv * 5 + dz) * 2 + kh) << 10));
                        acc[0][ox] = __builtin_amdgcn_mfma_f32_32x32x16_bf16(
                            a0, bf, acc[0][ox], 0, 0, 0);
                        acc[1][ox] = __builtin_amdgcn_mfma_f32_32x32x16_bf16(
                            a1, bf, acc[1][ox], 0, 0, 0);
                    }
                }
            }
            // END barrier: drains this step's prefetch (hidden by compute)
            __syncthreads();
        }
    }

    // epilogue: D lane l: co = l&31, z = zh*32 + rq*8 + (l>>5)*4 + (r&3)
#pragma unroll
    for (int oyi = 0; oyi < 2; ++oyi) {
        const int yy = y0 + oyp * 2 + oyi;
#pragma unroll
        for (int ox = 0; ox < 4; ++ox) {
            float* base = out +
                ((((size_t)b * 32 + l31) * 64 + (x0 + ox)) * 64 + yy) * 64 +
                zh * 32 + hi * 4;
#pragma unroll
            for (int rq = 0; rq < 4; ++rq) {
                f32x4 v = { acc[oyi][ox][rq * 4 + 0], acc[oyi][ox][rq * 4 + 1],
                            acc[oyi][ox][rq * 4 + 2], acc[oyi][ox][rq * 4 + 3] };
                *reinterpret_cast<f32x4*>(base + rq * 8) = v;
            }
        }
    }
}

// ---------------------------------------------------------------------------
extern "C" void kernel_launch(void* const* d_in, const int* in_sizes, int n_in,
                              void* d_out, int out_size, void* d_ws, size_t ws_size,
                              hipStream_t stream) {
    const float* x      = (const float*)d_in[0];
    const float* weight = (const float*)d_in[1];
    const float* w_sc0  = (const float*)d_in[2];
    const float* w_sc1  = (const float*)d_in[3];
    float* out = (float*)d_out;

    char* ws = (char*)d_ws;
    unsigned short* xt  = (unsigned short*)ws;                 // 33,554,432 B
    unsigned short* kwb = (unsigned short*)(ws + 33554432);    //    256,000 B
    unsigned short* zpg = (unsigned short*)(ws + 33810432);    //      4,096 B

    (void)hipFuncSetAttribute((const void*)conv_mfma,
                              hipFuncAttributeMaxDynamicSharedMemorySize,
                              120832);

    hipLaunchKernelGGL(build_pack, dim3(NTAP), dim3(128), 0, stream,
                       weight, w_sc0, w_sc1, kwb, (float4*)zpg);
    hipLaunchKernelGGL(xpose, dim3(64, 64, 2), dim3(256), 0, stream, x, xt);
    hipLaunchKernelGGL(conv_mfma, dim3(16, 8, 2), dim3(512), 120832, stream,
                       xt, kwb, zpg, out);
}